// Round 1
// baseline (1384.305 us; speedup 1.0000x reference)
//
#include <hip/hip_runtime.h>
#include <hip/hip_bf16.h>

// Problem dims (fixed): B=64, Te=1024, De=Dd=H=1024.
#define B_  64
#define TE  1024
#define K_  1024
#define HH  1024
#define MM  (B_ * TE)

typedef __bf16 bf16x8 __attribute__((ext_vector_type(8)));
typedef __bf16 bf16x4 __attribute__((ext_vector_type(4)));
typedef float  f32x4  __attribute__((ext_vector_type(4)));

__device__ __forceinline__ float fast_tanh(float x) {
    // tanh(x) = sign(x) * (1 - e^{-2|x|}) / (1 + e^{-2|x|}); branch-free, no overflow.
    float ax = __builtin_fabsf(x);
    float t  = __expf(-2.0f * ax);
    float r  = (1.0f - t) * __builtin_amdgcn_rcpf(1.0f + t);
    return __builtin_copysignf(r, x);
}

// ---------------------------------------------------------------- fp32 -> bf16 (small: Ua_w only)
__global__ void cvt_kernel(const float* __restrict__ in, __bf16* __restrict__ out, long n4) {
    long i = (long)blockIdx.x * blockDim.x + threadIdx.x;
    long stride = (long)gridDim.x * blockDim.x;
    const float4* in4 = (const float4*)in;
    bf16x4* out4 = (bf16x4*)out;
    for (long j = i; j < n4; j += stride) {
        float4 v = in4[j];
        bf16x4 o;
        o[0] = (__bf16)v.x; o[1] = (__bf16)v.y; o[2] = (__bf16)v.z; o[3] = (__bf16)v.w;
        out4[j] = o;
    }
}

// ---------------------------------------------------------------- Wa[b,h] = dec[b]·Wa_w[h] + Wa_b[h]
// Rewritten: dec row in registers (4x float4 per lane), float4 loads of Wa_w,
// unroll-4 over rows for ILP. One wave per h-row; grid (B, 16), 4 waves/block.
__global__ __launch_bounds__(256) void wa_kernel(const float* __restrict__ dec,
                                                 const float* __restrict__ Wa_w,
                                                 const float* __restrict__ Wa_b,
                                                 float* __restrict__ WaOut) {
    int b = blockIdx.x, hc = blockIdx.y;
    int wave = threadIdx.x >> 6, lane = threadIdx.x & 63;

    // lane holds dec[b, lane*16 .. lane*16+15]
    const float4* d4 = (const float4*)(dec + b * 1024);
    float4 dreg[4];
    #pragma unroll
    for (int j = 0; j < 4; j++) dreg[j] = d4[lane * 4 + j];

    #pragma unroll 4
    for (int i = 0; i < 16; i++) {
        int h = hc * 64 + wave * 16 + i;
        const float4* wr = (const float4*)(Wa_w + (long)h * 1024);
        float a = 0.0f;
        #pragma unroll
        for (int j = 0; j < 4; j++) {
            float4 v = wr[lane * 4 + j];
            a += v.x * dreg[j].x + v.y * dreg[j].y + v.z * dreg[j].z + v.w * dreg[j].w;
        }
        #pragma unroll
        for (int off = 32; off > 0; off >>= 1)
            a += __shfl_xor(a, off, 64);
        if (lane == 0) WaOut[b * 1024 + h] = a + Wa_b[h];
    }
}

// ---------------------------------------------------------------- fused score GEMM
// scores[m] += sum_h Va_w[h]*tanh(enc[m,:]·Ua_w[h,:] + Wa[b,h] + Ua_b[h])
// A staged directly from fp32 enc: reg prefetch -> packed cvt -> ds_write.
// y==0 blocks also emit the bf16 A tile to encB (consumed later by context).
// Block: 128 rows x 256 cols, single K pass; wave tile 64x128; KT=64; XOR swizzle.
// launch_bounds(256,3): 3 blocks/CU (LDS 3x50KB=150KB <= 160KB) for barrier-drain overlap.
#define MT 128
#define NP 256
#define KT 64

__global__ __launch_bounds__(256, 3) void score_gemm(
    const float* __restrict__ Af,    // [MM][1024] enc fp32
    __bf16* __restrict__ encB,       // [MM][1024] bf16 out (written by y==0 blocks)
    const __bf16* __restrict__ Bm,   // [1024][1024] Ua_w bf16
    const float* __restrict__ Wa,    // [64][1024]
    const float* __restrict__ Ua_b,  // [1024]
    const float* __restrict__ Va_w,  // [1024]
    float* __restrict__ scores)      // [MM], pre-zeroed, atomic accumulate
{
    __shared__ __bf16 sA[MT * KT];   // 16 KB, swizzled: row r, slot s' holds seg s'^(r&7)
    __shared__ __bf16 sB[NP * KT];   // 32 KB
    __shared__ float sVa[NP];
    __shared__ float sWU[NP];

    const int tid  = threadIdx.x;
    const int wave = tid >> 6;
    const int lane = tid & 63;
    const int quad = lane >> 4;
    const int l16  = lane & 15;
    const int wm   = wave >> 1;      // 0..1 -> 64-row half
    const int wn   = wave & 1;       // 0..1 -> 128-col half

    // bid -> (x strip, y quarter); groups of 32 bids = 8 XCD slots x 4 y sharing x.
    const int bid = blockIdx.x;
    const int grp = bid >> 5;
    const int r5  = bid & 31;
    const int y   = r5 >> 3;
    const int x   = grp * 8 + (r5 & 7);

    const int rowBase = x * MT;
    const int colBase = y * NP;
    const int b       = rowBase >> 10;
    const bool wb     = (y == 0);    // this block writes the bf16 A strip

    if (tid < NP) {
        int h = colBase + tid;
        sVa[tid] = Va_w[h];
        sWU[tid] = Wa[b * 1024 + h] + Ua_b[h];
    }

    // My 4 A chunks (8 bf16 each): c = i*256+tid; r=c>>3; seg=(c&7)^(r&7)
    int rr[4], sg[4];
    #pragma unroll
    for (int i = 0; i < 4; i++) {
        int c = i * 256 + tid;
        rr[i] = c >> 3;
        sg[i] = (c & 7) ^ (rr[i] & 7);
    }

    f32x4 acc[4][8] = {};            // [m-subtile s][n-subtile t]

    const long aBase = (long)rowBase * K_;
    const long bBase = (long)colBase * K_;

    float4 pre[4][2];
    #pragma unroll
    for (int i = 0; i < 4; i++) {    // prefetch A(k0=0)
        const float4* p = (const float4*)(Af + aBase + (long)rr[i] * K_ + sg[i] * 8);
        pre[i][0] = p[0]; pre[i][1] = p[1];
    }

    for (int k0 = 0; k0 < K_; k0 += KT) {
        __syncthreads();             // prior ds_reads done; prefetch loads drained here
        #pragma unroll
        for (int i = 0; i < 8; i++) {            // B: issue FIRST so loads progress under A-cvt
            int c = i * 256 + tid;
            int r = c >> 3, slot = c & 7;
            int seg = slot ^ (r & 7);
            __builtin_amdgcn_global_load_lds(
                (const __attribute__((address_space(1))) unsigned int*)(Bm + bBase + (long)r * K_ + k0 + seg * 8),
                (__attribute__((address_space(3))) unsigned int*)(sB + c * 8), 16, 0, 0);
        }
        #pragma unroll
        for (int i = 0; i < 4; i++) {            // A: cvt + ds_write (+ optional writeback)
            bf16x8 v;
            v[0] = (__bf16)pre[i][0].x; v[1] = (__bf16)pre[i][0].y;
            v[2] = (__bf16)pre[i][0].z; v[3] = (__bf16)pre[i][0].w;
            v[4] = (__bf16)pre[i][1].x; v[5] = (__bf16)pre[i][1].y;
            v[6] = (__bf16)pre[i][1].z; v[7] = (__bf16)pre[i][1].w;
            *(bf16x8*)(sA + (i * 256 + tid) * 8) = v;
            if (wb)
                *(bf16x8*)(encB + aBase + (long)rr[i] * K_ + k0 + sg[i] * 8) = v;
        }
        __syncthreads();             // staged data visible

        if (k0 + KT < K_) {          // issue next A prefetch; hides under MFMA phase
            #pragma unroll
            for (int i = 0; i < 4; i++) {
                const float4* p = (const float4*)(Af + aBase + (long)rr[i] * K_ + (k0 + KT) + sg[i] * 8);
                pre[i][0] = p[0]; pre[i][1] = p[1];
            }
        }

        #pragma unroll
        for (int ks = 0; ks < 2; ks++) {
            bf16x8 bfr[8];
            #pragma unroll
            for (int t = 0; t < 8; t++) {
                int r = wn * 128 + t * 16 + l16;
                int slot = (ks * 4 + quad) ^ (r & 7);
                bfr[t] = *(const bf16x8*)(sB + r * KT + slot * 8);
            }
            #pragma unroll
            for (int s = 0; s < 4; s++) {
                int r = wm * 64 + s * 16 + l16;
                int slot = (ks * 4 + quad) ^ (r & 7);
                bf16x8 af = *(const bf16x8*)(sA + r * KT + slot * 8);
                #pragma unroll
                for (int t = 0; t < 8; t++)
                    acc[s][t] = __builtin_amdgcn_mfma_f32_16x16x32_bf16(af, bfr[t], acc[s][t], 0, 0, 0);
            }
        }
    }

    // Epilogue. C/D layout: row = quad*4 + reg, col = l16.
    float rs[4][4] = {};
    #pragma unroll
    for (int s = 0; s < 4; s++)
        #pragma unroll
        for (int t = 0; t < 8; t++) {
            int hl = wn * 128 + t * 16 + l16;
            float va = sVa[hl], wu = sWU[hl];
            #pragma unroll
            for (int r = 0; r < 4; r++)
                rs[s][r] += va * fast_tanh(acc[s][t][r] + wu);
        }

    #pragma unroll
    for (int s = 0; s < 4; s++)
        #pragma unroll
        for (int r = 0; r < 4; r++) {
            float v = rs[s][r];
            v += __shfl_xor(v, 1, 64);
            v += __shfl_xor(v, 2, 64);
            v += __shfl_xor(v, 4, 64);
            v += __shfl_xor(v, 8, 64);
            if (l16 == 0)
                atomicAdd(&scores[rowBase + wm * 64 + s * 16 + quad * 4 + r], v);
        }
}

// ---------------------------------------------------------------- softmax over Te, in place
__global__ void softmax_kernel(float* __restrict__ s) {
    __shared__ float red[256];
    int b = blockIdx.x, tid = threadIdx.x;
    float4* row = (float4*)(s + b * 1024);
    float4 v = row[tid];
    float m = fmaxf(fmaxf(v.x, v.y), fmaxf(v.z, v.w));
    red[tid] = m; __syncthreads();
    for (int off = 128; off > 0; off >>= 1) {
        if (tid < off) red[tid] = fmaxf(red[tid], red[tid + off]);
        __syncthreads();
    }
    m = red[0]; __syncthreads();
    v.x = expf(v.x - m); v.y = expf(v.y - m); v.z = expf(v.z - m); v.w = expf(v.w - m);
    red[tid] = v.x + v.y + v.z + v.w; __syncthreads();
    for (int off = 128; off > 0; off >>= 1) {
        if (tid < off) red[tid] += red[tid + off];
        __syncthreads();
    }
    float inv = 1.0f / red[0];
    v.x *= inv; v.y *= inv; v.z *= inv; v.w *= inv;
    row[tid] = v;
}

// ---------------------------------------------------------------- context from bf16 enc
// bf16x8 (16B/lane) loads; 2 e-rows in flight; 8 accumulators per thread.
__global__ __launch_bounds__(256) void context_kernel(const __bf16* __restrict__ enc,
                                                      const float* __restrict__ w,
                                                      float* __restrict__ out) {
    int b = blockIdx.x, ec = blockIdx.y, tid = threadIdx.x;
    int eo = tid >> 7;               // 0..1 : which e-row pair member
    int dc = tid & 127;              // 0..127 : d chunk of 8
    const bf16x8* enc8 = (const bf16x8*)(enc + ((long)b * 1024 + ec * 64) * 1024);
    const float* wrow = w + b * 1024 + ec * 64;
    float acc[8] = {};
    #pragma unroll 4
    for (int e = eo; e < 64; e += 2) {
        float we = wrow[e];
        bf16x8 v = enc8[e * 128 + dc];
        #pragma unroll
        for (int j = 0; j < 8; j++) acc[j] += we * (float)v[j];
    }
    float* o = out + b * 1024 + dc * 8;
    #pragma unroll
    for (int j = 0; j < 8; j++) atomicAdd(o + j, acc[j]);
}

// ----------------------------------------------------------------
extern "C" void kernel_launch(void* const* d_in, const int* in_sizes, int n_in,
                              void* d_out, int out_size, void* d_ws, size_t ws_size,
                              hipStream_t stream) {
    (void)in_sizes; (void)n_in; (void)ws_size;
    const float* enc   = (const float*)d_in[0];
    const float* dec   = (const float*)d_in[1];
    const float* Wa_w  = (const float*)d_in[2];
    const float* Wa_b  = (const float*)d_in[3];
    const float* Ua_w  = (const float*)d_in[4];
    const float* Ua_b  = (const float*)d_in[5];
    const float* Va_w  = (const float*)d_in[6];
    // d_in[7] = Va_b: softmax-invariant -> dropped.
    float* out = (float*)d_out;

    char* w = (char*)d_ws;
    __bf16* encB = (__bf16*)w;  w += (size_t)MM * 1024 * 2;
    __bf16* uawB = (__bf16*)w;  w += (size_t)HH * 1024 * 2;
    float* WaBuf = (float*)w;   w += (size_t)B_ * HH * 4;
    float* scores = (float*)w;  w += (size_t)MM * 4;

    hipMemsetAsync(scores, 0, (size_t)MM * 4, stream);
    hipMemsetAsync(out, 0, (size_t)out_size * 4, stream);
    cvt_kernel<<<dim3(256), 256, 0, stream>>>(Ua_w, uawB, (long)HH * 1024 / 4);
    wa_kernel<<<dim3(B_, 16), 256, 0, stream>>>(dec, Wa_w, Wa_b, WaBuf);
    score_gemm<<<dim3((MM / MT) * (HH / NP)), 256, 0, stream>>>(enc, encB, uawB, WaBuf, Ua_b, Va_w, scores);
    softmax_kernel<<<dim3(B_), 256, 0, stream>>>(scores);
    context_kernel<<<dim3(B_, 16), 256, 0, stream>>>(encB, scores, out);
}

// Round 2
// 611.303 us; speedup vs baseline: 2.2645x; 2.2645x over previous
//
#include <hip/hip_runtime.h>
#include <hip/hip_bf16.h>

// Problem dims (fixed): B=64, Te=1024, De=Dd=H=1024.
#define B_  64
#define TE  1024
#define K_  1024
#define HH  1024
#define MM  (B_ * TE)

typedef __bf16 bf16x8 __attribute__((ext_vector_type(8)));
typedef __bf16 bf16x4 __attribute__((ext_vector_type(4)));
typedef float  f32x4  __attribute__((ext_vector_type(4)));

__device__ __forceinline__ float fast_tanh(float x) {
    // tanh(x) = sign(x) * (1 - e^{-2|x|}) / (1 + e^{-2|x|}); branch-free, no overflow.
    float ax = __builtin_fabsf(x);
    float t  = __expf(-2.0f * ax);
    float r  = (1.0f - t) * __builtin_amdgcn_rcpf(1.0f + t);
    return __builtin_copysignf(r, x);
}

// 4-slot XOR swizzle for KT=32 rows (depends on r&15 only).
#define SWZ(r) ((((r) & 3)) ^ ((((r) >> 2)) & 3))

// ---------------------------------------------------------------- fp32 -> bf16 (small: Ua_w only)
__global__ void cvt_kernel(const float* __restrict__ in, __bf16* __restrict__ out, long n4) {
    long i = (long)blockIdx.x * blockDim.x + threadIdx.x;
    long stride = (long)gridDim.x * blockDim.x;
    const float4* in4 = (const float4*)in;
    bf16x4* out4 = (bf16x4*)out;
    for (long j = i; j < n4; j += stride) {
        float4 v = in4[j];
        bf16x4 o;
        o[0] = (__bf16)v.x; o[1] = (__bf16)v.y; o[2] = (__bf16)v.z; o[3] = (__bf16)v.w;
        out4[j] = o;
    }
}

// ---------------------------------------------------------------- Wa[b,h] = dec[b]·Wa_w[h] + Wa_b[h]
__global__ __launch_bounds__(256) void wa_kernel(const float* __restrict__ dec,
                                                 const float* __restrict__ Wa_w,
                                                 const float* __restrict__ Wa_b,
                                                 float* __restrict__ WaOut) {
    int b = blockIdx.x, hc = blockIdx.y;
    int wave = threadIdx.x >> 6, lane = threadIdx.x & 63;

    const float4* d4 = (const float4*)(dec + b * 1024);
    float4 dreg[4];
    #pragma unroll
    for (int j = 0; j < 4; j++) dreg[j] = d4[lane * 4 + j];

    #pragma unroll 4
    for (int i = 0; i < 16; i++) {
        int h = hc * 64 + wave * 16 + i;
        const float4* wr = (const float4*)(Wa_w + (long)h * 1024);
        float a = 0.0f;
        #pragma unroll
        for (int j = 0; j < 4; j++) {
            float4 v = wr[lane * 4 + j];
            a += v.x * dreg[j].x + v.y * dreg[j].y + v.z * dreg[j].z + v.w * dreg[j].w;
        }
        #pragma unroll
        for (int off = 32; off > 0; off >>= 1)
            a += __shfl_xor(a, off, 64);
        if (lane == 0) WaOut[b * 1024 + h] = a + Wa_b[h];
    }
}

// ---------------------------------------------------------------- fused score GEMM
// scores[m] += sum_h Va_w[h]*tanh(enc[m,:]·Ua_w[h,:] + Wa[b,h] + Ua_b[h])
// KT=32, double-buffered LDS, ONE __syncthreads per K-step (T3-minimal):
//   step t: issue B(t+1) gload_lds + A(t+1) cvt/ds_write + A(t+2) reg prefetch,
//           THEN compute tile t, THEN barrier. Load latency hides under compute.
// 2 waves/SIMD is the register-file cap (acc=128 + ~110 VGPR): launch_bounds(256,2).
#define MT 128
#define NP 256
#define KT 32
#define NSTEP (K_ / KT)

__global__ __launch_bounds__(256, 2) void score_gemm(
    const float* __restrict__ Af,    // [MM][1024] enc fp32
    __bf16* __restrict__ encB,       // [MM][1024] bf16 out (written by y==0 blocks)
    const __bf16* __restrict__ Bm,   // [1024][1024] Ua_w bf16
    const float* __restrict__ Wa,    // [64][1024]
    const float* __restrict__ Ua_b,  // [1024]
    const float* __restrict__ Va_w,  // [1024]
    float* __restrict__ scores)      // [MM], pre-zeroed, atomic accumulate
{
    __shared__ __bf16 sA[2][MT * KT];   // 2 x 8 KB
    __shared__ __bf16 sB[2][NP * KT];   // 2 x 16 KB
    __shared__ float sVa[NP];
    __shared__ float sWU[NP];

    const int tid  = threadIdx.x;
    const int wave = tid >> 6;
    const int lane = tid & 63;
    const int quad = lane >> 4;
    const int l16  = lane & 15;
    const int wm   = wave >> 1;      // 0..1 -> 64-row half
    const int wn   = wave & 1;       // 0..1 -> 128-col half
    // read-side slot: rows are base(mult of 16)+l16, so SWZ(r)=SWZ(l16); uniform over s/t.
    const int slotq = quad ^ SWZ(l16);

    // bid -> (x strip, y quarter); groups of 32 bids = 8 XCD slots x 4 y sharing x.
    const int bid = blockIdx.x;
    const int grp = bid >> 5;
    const int r5  = bid & 31;
    const int y   = r5 >> 3;
    const int x   = grp * 8 + (r5 & 7);

    const int rowBase = x * MT;
    const int colBase = y * NP;
    const int b       = rowBase >> 10;
    const bool wb     = (y == 0);    // this block writes the bf16 A strip

    if (tid < NP) {
        int h = colBase + tid;
        sVa[tid] = Va_w[h];
        sWU[tid] = Wa[b * 1024 + h] + Ua_b[h];
    }

    const long aBase = (long)rowBase * K_;
    const long bBase = (long)colBase * K_;

    // A chunks (8 bf16 each): c = i*256+tid; r=c>>2; slot=c&3; seg=slot^SWZ(r). i=0..1
    int rrA[2], sgA[2];
    #pragma unroll
    for (int i = 0; i < 2; i++) {
        int c = i * 256 + tid;
        rrA[i] = c >> 2;
        sgA[i] = (c & 3) ^ SWZ(rrA[i]);
    }

    float4 pre[2][2];

    // ---- helpers -------------------------------------------------
    auto loadA = [&](int tk) {       // global fp32 -> pre regs (pre-swizzled source)
        int k = tk * KT;
        #pragma unroll
        for (int i = 0; i < 2; i++) {
            const float4* p = (const float4*)(Af + aBase + (long)rrA[i] * K_ + k + sgA[i] * 8);
            pre[i][0] = p[0]; pre[i][1] = p[1];
        }
    };
    auto cvtA = [&](__bf16* sAn, int tk) {   // pre regs -> bf16 -> LDS (+encB writeback)
        int k = tk * KT;
        #pragma unroll
        for (int i = 0; i < 2; i++) {
            bf16x8 v;
            v[0] = (__bf16)pre[i][0].x; v[1] = (__bf16)pre[i][0].y;
            v[2] = (__bf16)pre[i][0].z; v[3] = (__bf16)pre[i][0].w;
            v[4] = (__bf16)pre[i][1].x; v[5] = (__bf16)pre[i][1].y;
            v[6] = (__bf16)pre[i][1].z; v[7] = (__bf16)pre[i][1].w;
            *(bf16x8*)(sAn + (i * 256 + tid) * 8) = v;
            if (wb)
                *(bf16x8*)(encB + aBase + (long)rrA[i] * K_ + k + sgA[i] * 8) = v;
        }
    };
    auto stageB = [&](__bf16* sBn, int tk) { // 4 async 16B chunks per thread
        int k = tk * KT;
        #pragma unroll
        for (int i = 0; i < 4; i++) {
            int c = i * 256 + tid;
            int r = c >> 2;
            int seg = (c & 3) ^ SWZ(r);
            __builtin_amdgcn_global_load_lds(
                (const __attribute__((address_space(1))) unsigned int*)(Bm + bBase + (long)r * K_ + k + seg * 8),
                (__attribute__((address_space(3))) unsigned int*)(sBn + c * 8), 16, 0, 0);
        }
    };

    f32x4 acc[4][8] = {};            // [m-subtile s][n-subtile t]

    // ---- prologue: stage tile 0, prefetch A(1) -------------------
    loadA(0);
    stageB(sB[0], 0);
    cvtA(sA[0], 0);
    loadA(1);
    __syncthreads();

    // ---- main loop: 1 barrier per step ---------------------------
    #pragma unroll 2
    for (int t = 0; t < NSTEP; ++t) {
        const int cur = t & 1, nxt = cur ^ 1;

        if (t < NSTEP - 1) {
            stageB(sB[nxt], t + 1);      // async loads: drain at this step's barrier
            cvtA(sA[nxt], t + 1);        // consumes pre (holds A(t+1))
            if (t < NSTEP - 2) loadA(t + 2);
        }

        // compute tile t
        bf16x8 bfr[8];
        #pragma unroll
        for (int t8 = 0; t8 < 8; t8++) {
            int r = wn * 128 + t8 * 16 + l16;
            bfr[t8] = *(const bf16x8*)(sB[cur] + r * KT + slotq * 8);
        }
        #pragma unroll
        for (int s = 0; s < 4; s++) {
            int r = wm * 64 + s * 16 + l16;
            bf16x8 af = *(const bf16x8*)(sA[cur] + r * KT + slotq * 8);
            #pragma unroll
            for (int t8 = 0; t8 < 8; t8++)
                acc[s][t8] = __builtin_amdgcn_mfma_f32_16x16x32_bf16(af, bfr[t8], acc[s][t8], 0, 0, 0);
        }
        __syncthreads();
    }

    // Epilogue. C/D layout: row = quad*4 + reg, col = l16.
    float rs[4][4] = {};
    #pragma unroll
    for (int s = 0; s < 4; s++)
        #pragma unroll
        for (int t = 0; t < 8; t++) {
            int hl = wn * 128 + t * 16 + l16;
            float va = sVa[hl], wu = sWU[hl];
            #pragma unroll
            for (int r = 0; r < 4; r++)
                rs[s][r] += va * fast_tanh(acc[s][t][r] + wu);
        }

    #pragma unroll
    for (int s = 0; s < 4; s++)
        #pragma unroll
        for (int r = 0; r < 4; r++) {
            float v = rs[s][r];
            v += __shfl_xor(v, 1, 64);
            v += __shfl_xor(v, 2, 64);
            v += __shfl_xor(v, 4, 64);
            v += __shfl_xor(v, 8, 64);
            if (l16 == 0)
                atomicAdd(&scores[rowBase + wm * 64 + s * 16 + quad * 4 + r], v);
        }
}

// ---------------------------------------------------------------- softmax over Te, in place
__global__ void softmax_kernel(float* __restrict__ s) {
    __shared__ float red[256];
    int b = blockIdx.x, tid = threadIdx.x;
    float4* row = (float4*)(s + b * 1024);
    float4 v = row[tid];
    float m = fmaxf(fmaxf(v.x, v.y), fmaxf(v.z, v.w));
    red[tid] = m; __syncthreads();
    for (int off = 128; off > 0; off >>= 1) {
        if (tid < off) red[tid] = fmaxf(red[tid], red[tid + off]);
        __syncthreads();
    }
    m = red[0]; __syncthreads();
    v.x = expf(v.x - m); v.y = expf(v.y - m); v.z = expf(v.z - m); v.w = expf(v.w - m);
    red[tid] = v.x + v.y + v.z + v.w; __syncthreads();
    for (int off = 128; off > 0; off >>= 1) {
        if (tid < off) red[tid] += red[tid + off];
        __syncthreads();
    }
    float inv = 1.0f / red[0];
    v.x *= inv; v.y *= inv; v.z *= inv; v.w *= inv;
    row[tid] = v;
}

// ---------------------------------------------------------------- context partials (atomic-free)
// Block (b, ec): e-rows ec*128..+128, bf16x8 loads, LDS pair-reduce, direct store to pb.
__global__ __launch_bounds__(256) void context_partial(const __bf16* __restrict__ enc,
                                                       const float* __restrict__ w,
                                                       float* __restrict__ pb) {
    __shared__ float red[2][128][8];     // 8 KB
    int b = blockIdx.x, ec = blockIdx.y, tid = threadIdx.x;
    int eo = tid >> 7;               // 0..1 : e-row group
    int dc = tid & 127;              // 0..127 : d chunk of 8
    const bf16x8* enc8 = (const bf16x8*)(enc + ((long)b * 1024 + ec * 128) * 1024);
    const float* wrow = w + b * 1024 + ec * 128;
    float acc[8] = {};
    #pragma unroll 4
    for (int e = eo; e < 128; e += 2) {
        float we = wrow[e];
        bf16x8 v = enc8[e * 128 + dc];
        #pragma unroll
        for (int j = 0; j < 8; j++) acc[j] += we * (float)v[j];
    }
    #pragma unroll
    for (int j = 0; j < 8; j++) red[eo][dc][j] = acc[j];
    __syncthreads();
    if (eo == 0) {
        float* o = pb + ((long)(b * 8 + ec)) * 1024 + dc * 8;
        #pragma unroll
        for (int j = 0; j < 8; j++) o[j] = red[0][dc][j] + red[1][dc][j];
    }
}

// out[b][:] = sum_ec pb[b][ec][:]
__global__ void context_reduce(const float* __restrict__ pb, float* __restrict__ out) {
    int b = blockIdx.x, tid = threadIdx.x;
    const f32x4* p4 = (const f32x4*)pb;
    f32x4 s = {0.f, 0.f, 0.f, 0.f};
    #pragma unroll
    for (int ec = 0; ec < 8; ec++)
        s += p4[(b * 8 + ec) * 256 + tid];
    ((f32x4*)out)[b * 256 + tid] = s;
}

// ----------------------------------------------------------------
extern "C" void kernel_launch(void* const* d_in, const int* in_sizes, int n_in,
                              void* d_out, int out_size, void* d_ws, size_t ws_size,
                              hipStream_t stream) {
    (void)in_sizes; (void)n_in; (void)ws_size;
    const float* enc   = (const float*)d_in[0];
    const float* dec   = (const float*)d_in[1];
    const float* Wa_w  = (const float*)d_in[2];
    const float* Wa_b  = (const float*)d_in[3];
    const float* Ua_w  = (const float*)d_in[4];
    const float* Ua_b  = (const float*)d_in[5];
    const float* Va_w  = (const float*)d_in[6];
    // d_in[7] = Va_b: softmax-invariant -> dropped.
    float* out = (float*)d_out;

    char* w = (char*)d_ws;
    __bf16* encB = (__bf16*)w;  w += (size_t)MM * 1024 * 2;
    __bf16* uawB = (__bf16*)w;  w += (size_t)HH * 1024 * 2;
    float* WaBuf = (float*)w;   w += (size_t)B_ * HH * 4;
    float* scores = (float*)w;  w += (size_t)MM * 4;
    float* pb = (float*)w;      w += (size_t)B_ * 8 * 1024 * 4;

    hipMemsetAsync(scores, 0, (size_t)MM * 4, stream);
    cvt_kernel<<<dim3(256), 256, 0, stream>>>(Ua_w, uawB, (long)HH * 1024 / 4);
    wa_kernel<<<dim3(B_, 16), 256, 0, stream>>>(dec, Wa_w, Wa_b, WaBuf);
    score_gemm<<<dim3((MM / MT) * (HH / NP)), 256, 0, stream>>>(enc, encB, uawB, WaBuf, Ua_b, Va_w, scores);
    softmax_kernel<<<dim3(B_), 256, 0, stream>>>(scores);
    context_partial<<<dim3(B_, 8), 256, 0, stream>>>(encB, scores, pb);
    context_reduce<<<dim3(B_), 256, 0, stream>>>(pb, out);
}

// Round 3
// 563.683 us; speedup vs baseline: 2.4558x; 1.0845x over previous
//
#include <hip/hip_runtime.h>
#include <hip/hip_bf16.h>

// Problem dims (fixed): B=64, Te=1024, De=Dd=H=1024.
#define B_  64
#define TE  1024
#define K_  1024
#define HH  1024
#define MM  (B_ * TE)

typedef __bf16 bf16x8 __attribute__((ext_vector_type(8)));
typedef __bf16 bf16x4 __attribute__((ext_vector_type(4)));
typedef float  f32x4  __attribute__((ext_vector_type(4)));

__device__ __forceinline__ float fast_tanh(float x) {
    // tanh(x) = sign(x) * (1 - e^{-2|x|}) / (1 + e^{-2|x|}); branch-free, no overflow.
    float ax = __builtin_fabsf(x);
    float t  = __expf(-2.0f * ax);
    float r  = (1.0f - t) * __builtin_amdgcn_rcpf(1.0f + t);
    return __builtin_copysignf(r, x);
}

// ---------------------------------------------------------------- prep: cvt(Ua_w) + Wa GEMV, merged
// blocks 0..255: fp32->bf16 convert of Ua_w. blocks 256..1279: Wa[b,h] = dec[b]·Wa_w[h] + Wa_b[h].
__global__ __launch_bounds__(256) void prep_kernel(const float* __restrict__ Ua_w,
                                                   __bf16* __restrict__ uawB,
                                                   const float* __restrict__ dec,
                                                   const float* __restrict__ Wa_w,
                                                   const float* __restrict__ Wa_b,
                                                   float* __restrict__ WaOut) {
    int bid = blockIdx.x, tid = threadIdx.x;
    if (bid < 256) {
        const long n4 = (long)HH * 1024 / 4;
        const float4* in4 = (const float4*)Ua_w;
        bf16x4* out4 = (bf16x4*)uawB;
        for (long j = bid * 256 + tid; j < n4; j += 65536) {
            float4 v = in4[j];
            bf16x4 o;
            o[0] = (__bf16)v.x; o[1] = (__bf16)v.y; o[2] = (__bf16)v.z; o[3] = (__bf16)v.w;
            out4[j] = o;
        }
        return;
    }
    int wb = bid - 256;
    int b = wb >> 4, hc = wb & 15;
    int wave = tid >> 6, lane = tid & 63;

    const float4* d4 = (const float4*)(dec + b * 1024);
    float4 dreg[4];
    #pragma unroll
    for (int j = 0; j < 4; j++) dreg[j] = d4[lane * 4 + j];

    #pragma unroll 4
    for (int i = 0; i < 16; i++) {
        int h = hc * 64 + wave * 16 + i;
        const float4* wr = (const float4*)(Wa_w + (long)h * 1024);
        float a = 0.0f;
        #pragma unroll
        for (int j = 0; j < 4; j++) {
            float4 v = wr[lane * 4 + j];
            a += v.x * dreg[j].x + v.y * dreg[j].y + v.z * dreg[j].z + v.w * dreg[j].w;
        }
        #pragma unroll
        for (int off = 32; off > 0; off >>= 1)
            a += __shfl_xor(a, off, 64);
        if (lane == 0) WaOut[b * 1024 + h] = a + Wa_b[h];
    }
}

// ---------------------------------------------------------------- fused score GEMM
// scores[m] += sum_h Va_w[h]*tanh(enc[m,:]·Ua_w[h,:] + Wa[b,h] + Ua_b[h])
// m97 geometry: 128x128 tile, KT=64, acc[4][4] (64 regs), 33 KB LDS,
// launch_bounds(256,3) -> 3 blocks/CU (12 waves/CU) for cross-block pipelining.
// Proven round-0 structure: 2 barriers/K-step, 8-slot XOR swizzle (0 conflicts).
// y==0 blocks also emit the bf16 A tile to encB (consumed later by context).
#define MT 128
#define NP 128
#define KT 64

__global__ __launch_bounds__(256, 3) void score_gemm(
    const float* __restrict__ Af,    // [MM][1024] enc fp32
    __bf16* __restrict__ encB,       // [MM][1024] bf16 out (written by y==0 blocks)
    const __bf16* __restrict__ Bm,   // [1024][1024] Ua_w bf16
    const float* __restrict__ Wa,    // [64][1024]
    const float* __restrict__ Ua_b,  // [1024]
    const float* __restrict__ Va_w,  // [1024]
    float* __restrict__ scores)      // [MM], pre-zeroed, atomic accumulate
{
    __shared__ __bf16 sA[MT * KT];   // 16 KB, swizzled: row r, slot s' holds seg s'^(r&7)
    __shared__ __bf16 sB[NP * KT];   // 16 KB
    __shared__ float sVa[NP];
    __shared__ float sWU[NP];

    const int tid  = threadIdx.x;
    const int wave = tid >> 6;
    const int lane = tid & 63;
    const int quad = lane >> 4;
    const int l16  = lane & 15;
    const int wm   = wave >> 1;      // 0..1 -> 64-row half
    const int wn   = wave & 1;       // 0..1 -> 64-col half

    // bid -> (x strip, y eighth); groups of 64 bids = 8 XCD slots x 8 y sharing x.
    // Consecutive y-variants of one x land 8 bids apart -> SAME XCD -> A panel (512 KB)
    // + that strip's B panels (2 MB) L2-resident per XCD.
    const int bid = blockIdx.x;
    const int grp = bid >> 6;
    const int r6  = bid & 63;
    const int y   = r6 >> 3;
    const int x   = grp * 8 + (r6 & 7);

    const int rowBase = x * MT;
    const int colBase = y * NP;
    const int b       = rowBase >> 10;
    const bool wb     = (y == 0);    // this block writes the bf16 A strip

    if (tid < NP) {
        int h = colBase + tid;
        sVa[tid] = Va_w[h];
        sWU[tid] = Wa[b * 1024 + h] + Ua_b[h];
    }

    // My 4 A chunks (8 bf16 each): c = i*256+tid; r=c>>3; seg=(c&7)^(r&7)
    int rr[4], sg[4];
    #pragma unroll
    for (int i = 0; i < 4; i++) {
        int c = i * 256 + tid;
        rr[i] = c >> 3;
        sg[i] = (c & 7) ^ (rr[i] & 7);
    }

    f32x4 acc[4][4] = {};            // [m-subtile s][n-subtile t]

    const long aBase = (long)rowBase * K_;
    const long bBase = (long)colBase * K_;

    float4 pre[4][2];
    #pragma unroll
    for (int i = 0; i < 4; i++) {    // prefetch A(k0=0)
        const float4* p = (const float4*)(Af + aBase + (long)rr[i] * K_ + sg[i] * 8);
        pre[i][0] = p[0]; pre[i][1] = p[1];
    }

    for (int k0 = 0; k0 < K_; k0 += KT) {
        __syncthreads();             // prior ds_reads done; prefetch loads drained here
        #pragma unroll
        for (int i = 0; i < 4; i++) {            // B: 128x64 = 1024 chunks via async LDS
            int c = i * 256 + tid;
            int r = c >> 3, slot = c & 7;
            int seg = slot ^ (r & 7);
            __builtin_amdgcn_global_load_lds(
                (const __attribute__((address_space(1))) unsigned int*)(Bm + bBase + (long)r * K_ + k0 + seg * 8),
                (__attribute__((address_space(3))) unsigned int*)(sB + c * 8), 16, 0, 0);
        }
        #pragma unroll
        for (int i = 0; i < 4; i++) {            // A: cvt + ds_write (+ optional writeback)
            bf16x8 v;
            v[0] = (__bf16)pre[i][0].x; v[1] = (__bf16)pre[i][0].y;
            v[2] = (__bf16)pre[i][0].z; v[3] = (__bf16)pre[i][0].w;
            v[4] = (__bf16)pre[i][1].x; v[5] = (__bf16)pre[i][1].y;
            v[6] = (__bf16)pre[i][1].z; v[7] = (__bf16)pre[i][1].w;
            *(bf16x8*)(sA + (i * 256 + tid) * 8) = v;
            if (wb)
                *(bf16x8*)(encB + aBase + (long)rr[i] * K_ + k0 + sg[i] * 8) = v;
        }
        __syncthreads();             // staged data visible

        if (k0 + KT < K_) {          // issue next A prefetch; hides under MFMA phase
            #pragma unroll
            for (int i = 0; i < 4; i++) {
                const float4* p = (const float4*)(Af + aBase + (long)rr[i] * K_ + (k0 + KT) + sg[i] * 8);
                pre[i][0] = p[0]; pre[i][1] = p[1];
            }
        }

        #pragma unroll
        for (int ks = 0; ks < 2; ks++) {
            bf16x8 bfr[4];
            #pragma unroll
            for (int t = 0; t < 4; t++) {
                int r = wn * 64 + t * 16 + l16;
                int slot = (ks * 4 + quad) ^ (r & 7);
                bfr[t] = *(const bf16x8*)(sB + r * KT + slot * 8);
            }
            #pragma unroll
            for (int s = 0; s < 4; s++) {
                int r = wm * 64 + s * 16 + l16;
                int slot = (ks * 4 + quad) ^ (r & 7);
                bf16x8 af = *(const bf16x8*)(sA + r * KT + slot * 8);
                #pragma unroll
                for (int t = 0; t < 4; t++)
                    acc[s][t] = __builtin_amdgcn_mfma_f32_16x16x32_bf16(af, bfr[t], acc[s][t], 0, 0, 0);
            }
        }
    }

    // Epilogue. C/D layout: row = quad*4 + reg, col = l16.
    float rs[4][4] = {};
    #pragma unroll
    for (int s = 0; s < 4; s++)
        #pragma unroll
        for (int t = 0; t < 4; t++) {
            int hl = wn * 64 + t * 16 + l16;
            float va = sVa[hl], wu = sWU[hl];
            #pragma unroll
            for (int r = 0; r < 4; r++)
                rs[s][r] += va * fast_tanh(acc[s][t][r] + wu);
        }

    #pragma unroll
    for (int s = 0; s < 4; s++)
        #pragma unroll
        for (int r = 0; r < 4; r++) {
            float v = rs[s][r];
            v += __shfl_xor(v, 1, 64);
            v += __shfl_xor(v, 2, 64);
            v += __shfl_xor(v, 4, 64);
            v += __shfl_xor(v, 8, 64);
            if (l16 == 0)
                atomicAdd(&scores[rowBase + wm * 64 + s * 16 + quad * 4 + r], v);
        }
}

// ---------------------------------------------------------------- softmax over Te, in place
// Wave-shuffle reductions; 2 cross-wave barriers total (was ~17).
__global__ __launch_bounds__(256) void softmax_kernel(float* __restrict__ s) {
    __shared__ float red[8];
    int b = blockIdx.x, tid = threadIdx.x;
    int wave = tid >> 6, lane = tid & 63;
    float4* row = (float4*)(s + b * 1024);
    float4 v = row[tid];
    float m = fmaxf(fmaxf(v.x, v.y), fmaxf(v.z, v.w));
    #pragma unroll
    for (int off = 32; off > 0; off >>= 1)
        m = fmaxf(m, __shfl_xor(m, off, 64));
    if (lane == 0) red[wave] = m;
    __syncthreads();
    m = fmaxf(fmaxf(red[0], red[1]), fmaxf(red[2], red[3]));
    v.x = expf(v.x - m); v.y = expf(v.y - m); v.z = expf(v.z - m); v.w = expf(v.w - m);
    float sum = v.x + v.y + v.z + v.w;
    #pragma unroll
    for (int off = 32; off > 0; off >>= 1)
        sum += __shfl_xor(sum, off, 64);
    if (lane == 0) red[4 + wave] = sum;
    __syncthreads();
    float inv = 1.0f / (red[4] + red[5] + red[6] + red[7]);
    v.x *= inv; v.y *= inv; v.z *= inv; v.w *= inv;
    row[tid] = v;
}

// ---------------------------------------------------------------- context partials (atomic-free)
// Block (b, ec): e-rows ec*128..+128, bf16x8 loads, LDS pair-reduce, direct store to pb.
__global__ __launch_bounds__(256) void context_partial(const __bf16* __restrict__ enc,
                                                       const float* __restrict__ w,
                                                       float* __restrict__ pb) {
    __shared__ float red[2][128][8];     // 8 KB
    int b = blockIdx.x, ec = blockIdx.y, tid = threadIdx.x;
    int eo = tid >> 7;               // 0..1 : e-row group
    int dc = tid & 127;              // 0..127 : d chunk of 8
    const bf16x8* enc8 = (const bf16x8*)(enc + ((long)b * 1024 + ec * 128) * 1024);
    const float* wrow = w + b * 1024 + ec * 128;
    float acc[8] = {};
    #pragma unroll 4
    for (int e = eo; e < 128; e += 2) {
        float we = wrow[e];
        bf16x8 v = enc8[e * 128 + dc];
        #pragma unroll
        for (int j = 0; j < 8; j++) acc[j] += we * (float)v[j];
    }
    #pragma unroll
    for (int j = 0; j < 8; j++) red[eo][dc][j] = acc[j];
    __syncthreads();
    if (eo == 0) {
        float* o = pb + ((long)(b * 8 + ec)) * 1024 + dc * 8;
        #pragma unroll
        for (int j = 0; j < 8; j++) o[j] = red[0][dc][j] + red[1][dc][j];
    }
}

// out[b][:] = sum_ec pb[b][ec][:]
__global__ void context_reduce(const float* __restrict__ pb, float* __restrict__ out) {
    int b = blockIdx.x, tid = threadIdx.x;
    const f32x4* p4 = (const f32x4*)pb;
    f32x4 s = {0.f, 0.f, 0.f, 0.f};
    #pragma unroll
    for (int ec = 0; ec < 8; ec++)
        s += p4[(b * 8 + ec) * 256 + tid];
    ((f32x4*)out)[b * 256 + tid] = s;
}

// ----------------------------------------------------------------
extern "C" void kernel_launch(void* const* d_in, const int* in_sizes, int n_in,
                              void* d_out, int out_size, void* d_ws, size_t ws_size,
                              hipStream_t stream) {
    (void)in_sizes; (void)n_in; (void)ws_size;
    const float* enc   = (const float*)d_in[0];
    const float* dec   = (const float*)d_in[1];
    const float* Wa_w  = (const float*)d_in[2];
    const float* Wa_b  = (const float*)d_in[3];
    const float* Ua_w  = (const float*)d_in[4];
    const float* Ua_b  = (const float*)d_in[5];
    const float* Va_w  = (const float*)d_in[6];
    // d_in[7] = Va_b: softmax-invariant -> dropped.
    float* out = (float*)d_out;

    char* w = (char*)d_ws;
    __bf16* encB = (__bf16*)w;  w += (size_t)MM * 1024 * 2;
    __bf16* uawB = (__bf16*)w;  w += (size_t)HH * 1024 * 2;
    float* WaBuf = (float*)w;   w += (size_t)B_ * HH * 4;
    float* scores = (float*)w;  w += (size_t)MM * 4;
    float* pb = (float*)w;      w += (size_t)B_ * 8 * 1024 * 4;

    hipMemsetAsync(scores, 0, (size_t)MM * 4, stream);
    prep_kernel<<<dim3(256 + B_ * 16), 256, 0, stream>>>(Ua_w, uawB, dec, Wa_w, Wa_b, WaBuf);
    score_gemm<<<dim3((MM / MT) * (HH / NP)), 256, 0, stream>>>(enc, encB, uawB, WaBuf, Ua_b, Va_w, scores);
    softmax_kernel<<<dim3(B_), 256, 0, stream>>>(scores);
    context_partial<<<dim3(B_, 8), 256, 0, stream>>>(encB, scores, pb);
    context_reduce<<<dim3(B_), 256, 0, stream>>>(pb, out);
}